// Round 14
// baseline (115.204 us; speedup 1.0000x reference)
//
#include <hip/hip_runtime.h>
#include <stdint.h>
#include <stddef.h>

#define TB 2048
#define KDIM 1024
#define NH 16
#define HD 64

typedef __attribute__((ext_vector_type(8))) __bf16 bf16x8;
typedef __attribute__((ext_vector_type(2))) float f32x2;
typedef __attribute__((ext_vector_type(4))) float f32x4;
typedef __attribute__((ext_vector_type(16))) float f32x16;
typedef __attribute__((ext_vector_type(4))) unsigned short u16x4;
typedef __attribute__((ext_vector_type(8))) unsigned short u16x8;
typedef __attribute__((ext_vector_type(4))) unsigned u32x4;
typedef __attribute__((ext_vector_type(2))) unsigned u32x2;

static __device__ __forceinline__ unsigned short f2bf(float f) {
  unsigned u = __builtin_bit_cast(unsigned, f);
  return (unsigned short)((u + 0x7FFFu + ((u >> 16) & 1u)) >> 16);
}

static __device__ __forceinline__ bf16x8 ld_frag(const unsigned short* p) {
  u16x8 v = *(const u16x8*)p;
  return __builtin_bit_cast(bf16x8, v);
}

// global(16B per lane) -> LDS, linear lane order. LDS ptr must be wave-uniform.
static __device__ __forceinline__ void gload_lds16(const void* g, void* l) {
  auto gp = (const __attribute__((address_space(1))) unsigned int*)(uintptr_t)g;
  auto lp = (__attribute__((address_space(3))) unsigned int*)(unsigned int)(uintptr_t)l;
  __builtin_amdgcn_global_load_lds(gp, lp, 16, 0, 0);
}

static __device__ __forceinline__ float fast_exp2(float x) {
  float r;
  asm("v_exp_f32 %0, %1" : "=v"(r) : "v"(x));
  return r;
}

static __device__ __forceinline__ unsigned cvt_pk(float a, float b) {
  unsigned r;
  asm("v_cvt_pk_bf16_f32 %0, %1, %2" : "=v"(r) : "v"(a), "v"(b));
  return r;
}

static __device__ __forceinline__ u32x2 permswap(unsigned a, unsigned b) {
  return __builtin_amdgcn_permlane32_swap(a, b, false, false);
}

static __device__ __forceinline__ f32x2 pk_fma(f32x2 a, f32x2 b, f32x2 c) {
  f32x2 d;
  asm("v_pk_fma_f32 %0, %1, %2, %3" : "=v"(d) : "v"(a), "v"(b), "v"(c));
  return d;
}
static __device__ __forceinline__ f32x2 pk_add(f32x2 a, f32x2 b) {
  f32x2 d;
  asm("v_pk_add_f32 %0, %1, %2" : "=v"(d) : "v"(a), "v"(b));
  return d;
}

// ---------------- fused f32 -> bf16 convert (8 elems/thread) ----------------
__global__ __launch_bounds__(256) void k_cvt_all(
    const float* __restrict__ x, const float* __restrict__ Wq,
    const float* __restrict__ Wk, const float* __restrict__ Wv,
    const float* __restrict__ Wo, unsigned short* __restrict__ xb,
    unsigned short* __restrict__ wb) {
  int bb = blockIdx.x;
  const float* src;
  unsigned short* dst;
  int i;
  if (bb < 2048) {
    src = x; dst = xb; i = bb * 256 + threadIdx.x;
  } else {
    int wsel = (bb - 2048) >> 9;
    src = (wsel == 0) ? Wq : (wsel == 1) ? Wk : (wsel == 2) ? Wv : Wo;
    dst = wb + (size_t)wsel * (KDIM * KDIM);
    i = ((bb - 2048) & 511) * 256 + threadIdx.x;
  }
  const float4* p = (const float4*)src + (size_t)i * 2;
  float4 a = p[0], b = p[1];
  u16x8 o;
  o[0] = f2bf(a.x); o[1] = f2bf(a.y); o[2] = f2bf(a.z); o[3] = f2bf(a.w);
  o[4] = f2bf(b.x); o[5] = f2bf(b.y); o[6] = f2bf(b.z); o[7] = f2bf(b.w);
  *((u16x8*)dst + i) = o;
}

// ---------------- GEMM C = A @ W^T (A:[M,K] bf16, W:[N,K] bf16) ----------------
// 128x128 tile, BK=32, double-buffered LDS (2 x 16 KB), 4 waves (2x2),
// 16x16x32 MFMA. Stage-at-top + counted-wait-at-bottom with the PINNED idiom
// (vmcnt + raw s_barrier + sched_barrier(0)) — loads for k+1 cover their L2
// latency under iteration k's compute, instead of draining at a barrier
// right after issue (the m97 stall). Swizzle for 64 B rows:
// source blk = (c&3)^((rr>>2)&3), read blk = g^((r>>2)&3) — <=2-way banks,
// and the same permutation on A and B cancels in the contraction.
template <int MODE>  // 0: bf16 out. 1: f32 out + bias. 2: bf16 Vt[b,h,d,t] out.
static __device__ __forceinline__ void gemm_body(
    const unsigned short* __restrict__ A, const unsigned short* __restrict__ W,
    unsigned short* __restrict__ Cb, float* __restrict__ Cf,
    const float* __restrict__ bias, int by, int bx,
    unsigned short* As, unsigned short* Bs) {
  const int K = KDIM, N = KDIM;
  int tid = threadIdx.x, lane = tid & 63, wid = tid >> 6;
  int r = lane & 15, g = lane >> 4;
  int wm = wid >> 1, wn = wid & 1;

  f32x4 acc[4][4];
#pragma unroll
  for (int m = 0; m < 4; ++m)
#pragma unroll
    for (int n = 0; n < 4; ++n) acc[m][n] = (f32x4){0.f, 0.f, 0.f, 0.f};

  const unsigned short* Ag = A + (size_t)(by * 128) * K;
  const unsigned short* Wg = W + (size_t)(bx * 128) * K;

  // stage one BK=32 slab (A: 128x32, B: 128x32) into buffer `buf`
  auto stage = [&](int k0, int buf) {
#pragma unroll
    for (int it = 0; it < 2; ++it) {
      int base = it * 256 + wid * 64;   // chunk base (wave-uniform)
      int c = base + lane;              // chunk 0..511; rr = c>>2, col = c&3
      int rr = c >> 2;
      int bl = (c & 3) ^ ((rr >> 2) & 3);   // pre-swizzled source block
      gload_lds16(Ag + (size_t)rr * K + k0 + bl * 8, &As[buf * 4096 + base * 8]);
      gload_lds16(Wg + (size_t)rr * K + k0 + bl * 8, &Bs[buf * 4096 + base * 8]);
    }
  };

  stage(0, 0);
  asm volatile("s_waitcnt vmcnt(0)" ::: "memory");
  __builtin_amdgcn_s_barrier();
  __builtin_amdgcn_sched_barrier(0);

  for (int kk = 0; kk < 32; ++kk) {
    int buf = kk & 1;
    // stage kk+1 into the buffer everyone finished reading at the last barrier
    if (kk + 1 < 32) stage((kk + 1) * 32, buf ^ 1);

    bf16x8 af[4], bf[4];
    int bl = g ^ ((r >> 2) & 3);
#pragma unroll
    for (int m = 0; m < 4; ++m) {
      int row = wm * 64 + m * 16 + r;
      af[m] = ld_frag(&As[buf * 4096 + row * 32 + bl * 8]);
    }
#pragma unroll
    for (int n = 0; n < 4; ++n) {
      int row = wn * 64 + n * 16 + r;
      bf[n] = ld_frag(&Bs[buf * 4096 + row * 32 + bl * 8]);
    }
    __builtin_amdgcn_s_setprio(1);
#pragma unroll
    for (int m = 0; m < 4; ++m)
#pragma unroll
      for (int n = 0; n < 4; ++n)
        acc[m][n] = __builtin_amdgcn_mfma_f32_16x16x32_bf16(af[m], bf[n], acc[m][n], 0, 0, 0);
    __builtin_amdgcn_s_setprio(0);

    // pinned barrier: my stage(kk+1) loads landed; everyone done reading buf
    asm volatile("s_waitcnt vmcnt(0)" ::: "memory");
    __builtin_amdgcn_s_barrier();
    __builtin_amdgcn_sched_barrier(0);
  }

#pragma unroll
  for (int m = 0; m < 4; ++m)
#pragma unroll
    for (int n = 0; n < 4; ++n) {
      int col = bx * 128 + wn * 64 + n * 16 + r;
      if (MODE == 2) {
        int hq = col >> 6, dq = col & 63;
        int row0 = by * 128 + wm * 64 + m * 16 + g * 4;
        int bq = row0 >> 11, tq = row0 & 2047;
        u16x4 pv;
#pragma unroll
        for (int j = 0; j < 4; ++j) pv[j] = f2bf(acc[m][n][j]);
        *(u16x4*)&Cb[(((size_t)(bq * NH + hq)) * HD + dq) * TB + tq] = pv;
      } else {
#pragma unroll
        for (int j = 0; j < 4; ++j) {
          int row = by * 128 + wm * 64 + m * 16 + g * 4 + j;
          if (MODE == 0)
            Cb[(size_t)row * N + col] = f2bf(acc[m][n][j]);
          else
            Cf[(size_t)row * N + col] = acc[m][n][j] + bias[col];
        }
      }
    }
}

__global__ __launch_bounds__(256) void k_gemm_qkv(
    const unsigned short* __restrict__ X,
    const unsigned short* __restrict__ Wq, const unsigned short* __restrict__ Wk,
    const unsigned short* __restrict__ Wv,
    unsigned short* __restrict__ Q, unsigned short* __restrict__ Kp,
    unsigned short* __restrict__ Vt) {
  __shared__ __align__(16) unsigned short As[8192];
  __shared__ __align__(16) unsigned short Bs[8192];
  // bijective XCD swizzle (768 = 8 x 96): XCD xcd owns by-panels 4*xcd..4*xcd+3
  int bidx = blockIdx.x;
  int xcd = bidx & 7, slot = bidx >> 3;
  int by = xcd * 4 + slot / 24;
  int bxx = slot % 24;
  int which = bxx >> 3, bx = bxx & 7;
  if (which == 2) {
    gemm_body<2>(X, Wv, Vt, nullptr, nullptr, by, bx, As, Bs);
  } else {
    const unsigned short* W = which ? Wk : Wq;
    unsigned short* C = which ? Kp : Q;
    gemm_body<0>(X, W, C, nullptr, nullptr, by, bx, As, Bs);
  }
}

__global__ __launch_bounds__(256) void k_gemm_out(
    const unsigned short* __restrict__ AO, const unsigned short* __restrict__ Wo,
    float* __restrict__ out, const float* __restrict__ bias) {
  __shared__ __align__(16) unsigned short As[8192];
  __shared__ __align__(16) unsigned short Bs[8192];
  // bijective XCD swizzle (256 = 8 x 32)
  int bidx = blockIdx.x;
  int xcd = bidx & 7, slot = bidx >> 3;
  int by = xcd * 4 + slot / 8;
  int bx = slot & 7;
  gemm_body<1>(AO, Wo, nullptr, out, bias, by, bx, As, Bs);
}

// ---------------- flash attention, 2 tiles per barrier period ----------------
// grid: 512 blocks (32 bh x 16 qt; bh = blockIdx&31 is XCD-affine) x 512 thr
// (8 waves). Wave w = (wl = w&3: 32 q-rows) x (kh = w>>2: key-half of each
// staged 64-key tile). 16 units x 2 tiles; double-buffered 2-tile units
// (64 KB LDS) with the PINNED sync idiom. FIXED-MAX softmax: P = exp(s/8-10).
__global__ __launch_bounds__(512, 4) void k_attn(
    const unsigned short* __restrict__ Q, const unsigned short* __restrict__ Kp,
    const unsigned short* __restrict__ Vt, unsigned short* __restrict__ AO) {
  __shared__ __align__(16) unsigned short LDSb[8 * 4096];  // 64 KB
  unsigned short* KsB = LDSb;             // [buf][tt][64 keys][64 d], swizzled
  unsigned short* VsB = LDSb + 4 * 4096;  // [buf][tt][64 d][64 keys], swizzled

  int qt = blockIdx.x >> 5, bh = blockIdx.x & 31;
  int b = bh >> 4, h = bh & 15;
  int tid = threadIdx.x, lane = tid & 63, w = tid >> 6;
  int wl = w & 3, kh = w >> 2;
  int q = lane & 31, hh = lane >> 5;
  const float LOG2E = 1.44269504f;
  const int NU = 16;                // 16 units x 128 keys = 2048

  const unsigned short* Qp =
      Q + ((size_t)(b * TB + qt * 128 + wl * 32 + q)) * KDIM + h * HD;
  bf16x8 qf[4];
#pragma unroll
  for (int f = 0; f < 4; ++f) qf[f] = ld_frag(&Qp[16 * f + 8 * hh]);

  f32x16 o0, o1;
#pragma unroll
  for (int i = 0; i < 16; ++i) { o0[i] = 0.f; o1[i] = 0.f; }
  float l_run = 0.f;

  // staging addresses (each wave stages 1KB of K + 1KB of V per tile)
  int c = w * 64 + lane;
  int rr = c >> 3;
  int blk = (c & 7) ^ (rr & 7);            // pre-swizzled global source
  const unsigned short* Kg =
      Kp + (size_t)(b * TB) * KDIM + h * HD + (size_t)rr * KDIM + blk * 8;
  const unsigned short* Vg =
      Vt + (size_t)bh * HD * TB + (size_t)rr * TB + blk * 8;
  int ldst = w * 512;  // u16 offset of this wave's 1KB chunk

  auto stage = [&](int u, int buf) {
#pragma unroll
    for (int tt = 0; tt < 2; ++tt) {
      int kt = u * 2 + tt;
      int slot = buf * 2 + tt;
      gload_lds16(Kg + (size_t)kt * 64 * KDIM, &KsB[slot * 4096 + ldst]);
      gload_lds16(Vg + kt * 64, &VsB[slot * 4096 + ldst]);
    }
  };

  stage(0, 0);
  asm volatile("s_waitcnt vmcnt(0)" ::: "memory");
  __builtin_amdgcn_s_barrier();
  __builtin_amdgcn_sched_barrier(0);

  const float c1 = 0.125f * LOG2E;       // score scale folded into exp2
  const float c2 = 10.0f * LOG2E;        // fixed max shift
  f32x2 c1v; c1v[0] = c1; c1v[1] = c1;
  f32x2 c2v; c2v[0] = -c2; c2v[1] = -c2;

  for (int u = 0; u < NU; ++u) {
    int buf = u & 1;
    if (u + 1 < NU) stage(u + 1, buf ^ 1);

#pragma unroll
    for (int tt = 0; tt < 2; ++tt) {
      int slot = buf * 2 + tt;
      // S^T(32 keys x 32 q) = K_chunk @ Q^T
      const unsigned short* Kc = &KsB[slot * 4096];
      f32x16 st;
#pragma unroll
      for (int i = 0; i < 16; ++i) st[i] = 0.f;
      __builtin_amdgcn_s_setprio(1);
#pragma unroll
      for (int f = 0; f < 4; ++f) {
        int row = kh * 32 + q;
        int bl = (2 * f + hh) ^ (q & 7);
        bf16x8 kf = ld_frag(&Kc[row * 64 + bl * 8]);
        st = __builtin_amdgcn_mfma_f32_32x32x16_bf16(kf, qf[f], st, 0, 0, 0);
      }
      __builtin_amdgcn_s_setprio(0);

      // P = exp2(s*c1 - c2), packed bf16 fragments in-register (T12)
      f32x2 rsv; rsv[0] = 0.f; rsv[1] = 0.f;
      unsigned d[8];
#pragma unroll
      for (int i = 0; i < 8; ++i) {
        f32x2 p; p[0] = st[2 * i]; p[1] = st[2 * i + 1];
        p = pk_fma(p, c1v, c2v);
        f32x2 e; e[0] = fast_exp2(p[0]); e[1] = fast_exp2(p[1]);
        rsv = pk_add(rsv, e);
        d[i] = cvt_pk(e[0], e[1]);
      }
      u32x2 r1 = permswap(d[0], d[2]);
      u32x2 r2 = permswap(d[1], d[3]);
      u32x2 r3 = permswap(d[4], d[6]);
      u32x2 r4 = permswap(d[5], d[7]);
      u32x4 t0; t0[0] = r1.x; t0[1] = r2.x; t0[2] = r1.y; t0[3] = r2.y;
      u32x4 t1; t1[0] = r3.x; t1[1] = r4.x; t1[2] = r3.y; t1[3] = r4.y;
      bf16x8 pa0 = __builtin_bit_cast(bf16x8, t0);
      bf16x8 pa1 = __builtin_bit_cast(bf16x8, t1);
      float rs = rsv[0] + rsv[1];
      rs += __shfl_xor(rs, 32);
      l_run += rs;

      // O += P @ V (this wave's 32-key chunk)
      const unsigned short* Vc = &VsB[slot * 4096];
      __builtin_amdgcn_s_setprio(1);
      {
        int bl0 = (kh * 4 + hh) ^ (q & 7);
        int bl1 = (kh * 4 + 2 + hh) ^ (q & 7);
        bf16x8 v00 = ld_frag(&Vc[q * 64 + bl0 * 8]);
        bf16x8 v01 = ld_frag(&Vc[(32 + q) * 64 + bl0 * 8]);
        bf16x8 v10 = ld_frag(&Vc[q * 64 + bl1 * 8]);
        bf16x8 v11 = ld_frag(&Vc[(32 + q) * 64 + bl1 * 8]);
        o0 = __builtin_amdgcn_mfma_f32_32x32x16_bf16(pa0, v00, o0, 0, 0, 0);
        o1 = __builtin_amdgcn_mfma_f32_32x32x16_bf16(pa0, v01, o1, 0, 0, 0);
        o0 = __builtin_amdgcn_mfma_f32_32x32x16_bf16(pa1, v10, o0, 0, 0, 0);
        o1 = __builtin_amdgcn_mfma_f32_32x32x16_bf16(pa1, v11, o1, 0, 0, 0);
      }
      __builtin_amdgcn_s_setprio(0);
    }

    // pinned barrier: my stage(u+1) loads landed; everyone done reading buf
    asm volatile("s_waitcnt vmcnt(0)" ::: "memory");
    __builtin_amdgcn_s_barrier();
    __builtin_amdgcn_sched_barrier(0);
  }

  // -------- in-block kh merge via LDS (overlay on staging buffers) ----------
  float* Osw = (float*)LDSb;            // 32 KB
  float* MLb = Osw + 8192;              // 128 floats
  if (kh) {
#pragma unroll
    for (int p = 0; p < 16; ++p) {
      Osw[p * 256 + wl * 64 + lane]        = o0[p];
      Osw[(16 + p) * 256 + wl * 64 + lane] = o1[p];
    }
    if (!hh) MLb[wl * 32 + q] = l_run;
  }
  __syncthreads();
  if (!kh) {
    float il = 1.f / (l_run + MLb[wl * 32 + q]);
#pragma unroll
    for (int p = 0; p < 16; ++p) {
      int qr = (p & 3) + 8 * (p >> 2) + 4 * hh;
      float ip = __shfl(il, qr);
      float v0 = (o0[p] + Osw[p * 256 + wl * 64 + lane]) * ip;
      float v1 = (o1[p] + Osw[(16 + p) * 256 + wl * 64 + lane]) * ip;
      int row = qt * 128 + wl * 32 + qr;
      size_t base = ((size_t)(b * TB + row)) * KDIM + h * HD;
      AO[base + q]      = f2bf(v0);
      AO[base + 32 + q] = f2bf(v1);
    }
  }
}

// ---------------- launch ----------------
extern "C" void kernel_launch(void* const* d_in, const int* in_sizes, int n_in,
                              void* d_out, int out_size, void* d_ws, size_t ws_size,
                              hipStream_t stream) {
  const float* x  = (const float*)d_in[0];
  const float* Wq = (const float*)d_in[1];
  const float* Wk = (const float*)d_in[2];
  const float* Wv = (const float*)d_in[3];
  const float* Wo = (const float*)d_in[4];
  const float* bo = (const float*)d_in[5];

  char* ws = (char*)d_ws;
  const size_t MB = 1 << 20;
  unsigned short* xb  = (unsigned short*)(ws + 0 * MB);   // 8 MiB
  unsigned short* wqb = (unsigned short*)(ws + 8 * MB);   // 4 x 2 MiB contiguous
  unsigned short* wkb = (unsigned short*)(ws + 10 * MB);
  unsigned short* wvb = (unsigned short*)(ws + 12 * MB);
  unsigned short* wob = (unsigned short*)(ws + 14 * MB);
  unsigned short* Qb  = (unsigned short*)(ws + 16 * MB);  // 8 MiB
  unsigned short* Kb  = (unsigned short*)(ws + 24 * MB);
  unsigned short* Vtb = (unsigned short*)(ws + 32 * MB);
  unsigned short* AOb = (unsigned short*)(ws + 40 * MB);  // ends at 48 MiB

  k_cvt_all<<<4096, 256, 0, stream>>>(x, Wq, Wk, Wv, Wo, xb, wqb);
  k_gemm_qkv<<<32 * 24, 256, 0, stream>>>(xb, wqb, wkb, wvb, Qb, Kb, Vtb);
  k_attn<<<512, 512, 0, stream>>>(Qb, Kb, Vtb, AOb);
  k_gemm_out<<<256, 256, 0, stream>>>(AOb, wob, (float*)d_out, bo);
}

// Round 15
// 113.498 us; speedup vs baseline: 1.0150x; 1.0150x over previous
//
#include <hip/hip_runtime.h>
#include <stdint.h>
#include <stddef.h>

#define TB 2048
#define KDIM 1024
#define NH 16
#define HD 64

typedef __attribute__((ext_vector_type(8))) __bf16 bf16x8;
typedef __attribute__((ext_vector_type(2))) float f32x2;
typedef __attribute__((ext_vector_type(4))) float f32x4;
typedef __attribute__((ext_vector_type(16))) float f32x16;
typedef __attribute__((ext_vector_type(4))) unsigned short u16x4;
typedef __attribute__((ext_vector_type(8))) unsigned short u16x8;
typedef __attribute__((ext_vector_type(4))) unsigned u32x4;
typedef __attribute__((ext_vector_type(2))) unsigned u32x2;

static __device__ __forceinline__ unsigned short f2bf(float f) {
  unsigned u = __builtin_bit_cast(unsigned, f);
  return (unsigned short)((u + 0x7FFFu + ((u >> 16) & 1u)) >> 16);
}

static __device__ __forceinline__ bf16x8 ld_frag(const unsigned short* p) {
  u16x8 v = *(const u16x8*)p;
  return __builtin_bit_cast(bf16x8, v);
}

// global(16B per lane) -> LDS, linear lane order. LDS ptr must be wave-uniform.
static __device__ __forceinline__ void gload_lds16(const void* g, void* l) {
  auto gp = (const __attribute__((address_space(1))) unsigned int*)(uintptr_t)g;
  auto lp = (__attribute__((address_space(3))) unsigned int*)(unsigned int)(uintptr_t)l;
  __builtin_amdgcn_global_load_lds(gp, lp, 16, 0, 0);
}

static __device__ __forceinline__ float fast_exp2(float x) {
  float r;
  asm("v_exp_f32 %0, %1" : "=v"(r) : "v"(x));
  return r;
}

static __device__ __forceinline__ unsigned cvt_pk(float a, float b) {
  unsigned r;
  asm("v_cvt_pk_bf16_f32 %0, %1, %2" : "=v"(r) : "v"(a), "v"(b));
  return r;
}

static __device__ __forceinline__ u32x2 permswap(unsigned a, unsigned b) {
  return __builtin_amdgcn_permlane32_swap(a, b, false, false);
}

static __device__ __forceinline__ f32x2 pk_fma(f32x2 a, f32x2 b, f32x2 c) {
  f32x2 d;
  asm("v_pk_fma_f32 %0, %1, %2, %3" : "=v"(d) : "v"(a), "v"(b), "v"(c));
  return d;
}
static __device__ __forceinline__ f32x2 pk_add(f32x2 a, f32x2 b) {
  f32x2 d;
  asm("v_pk_add_f32 %0, %1, %2" : "=v"(d) : "v"(a), "v"(b));
  return d;
}

// ---------------- fused f32 -> bf16 convert (8 elems/thread) ----------------
__global__ __launch_bounds__(256) void k_cvt_all(
    const float* __restrict__ x, const float* __restrict__ Wq,
    const float* __restrict__ Wk, const float* __restrict__ Wv,
    const float* __restrict__ Wo, unsigned short* __restrict__ xb,
    unsigned short* __restrict__ wb) {
  int bb = blockIdx.x;
  const float* src;
  unsigned short* dst;
  int i;
  if (bb < 2048) {
    src = x; dst = xb; i = bb * 256 + threadIdx.x;
  } else {
    int wsel = (bb - 2048) >> 9;
    src = (wsel == 0) ? Wq : (wsel == 1) ? Wk : (wsel == 2) ? Wv : Wo;
    dst = wb + (size_t)wsel * (KDIM * KDIM);
    i = ((bb - 2048) & 511) * 256 + threadIdx.x;
  }
  const float4* p = (const float4*)src + (size_t)i * 2;
  float4 a = p[0], b = p[1];
  u16x8 o;
  o[0] = f2bf(a.x); o[1] = f2bf(a.y); o[2] = f2bf(a.z); o[3] = f2bf(a.w);
  o[4] = f2bf(b.x); o[5] = f2bf(b.y); o[6] = f2bf(b.z); o[7] = f2bf(b.w);
  *((u16x8*)dst + i) = o;
}

// ---------------- GEMM C = A @ W^T (A:[M,K] bf16, W:[N,K] bf16) ----------------
// 128x128 tile, BK=32, TRI-buffered LDS (3 x 8 KB per operand, 48 KB), 4 waves
// (2x2), 16x16x32 MFMA. T3/T4 pipeline: iter kk stages kk+2, computes buf kk%3,
// then waits vmcnt(4) — only stage kk+1's 4 loads (kk+2's stay in flight, ~2
// compute phases of latency cover; never drains to 0 in steady state) + raw
// s_barrier + sched_barrier(0) (pinned, motion-proof). R14's vmcnt(0)-drain
// variant gave loads only one 128-cy compute phase against ~400-cy L2 latency.
template <int MODE>  // 0: bf16 out. 1: f32 out + bias. 2: bf16 Vt[b,h,d,t] out.
static __device__ __forceinline__ void gemm_body(
    const unsigned short* __restrict__ A, const unsigned short* __restrict__ W,
    unsigned short* __restrict__ Cb, float* __restrict__ Cf,
    const float* __restrict__ bias, int by, int bx,
    unsigned short* As, unsigned short* Bs) {
  const int K = KDIM, N = KDIM;
  int tid = threadIdx.x, lane = tid & 63, wid = tid >> 6;
  int r = lane & 15, g = lane >> 4;
  int wm = wid >> 1, wn = wid & 1;

  f32x4 acc[4][4];
#pragma unroll
  for (int m = 0; m < 4; ++m)
#pragma unroll
    for (int n = 0; n < 4; ++n) acc[m][n] = (f32x4){0.f, 0.f, 0.f, 0.f};

  const unsigned short* Ag = A + (size_t)(by * 128) * K;
  const unsigned short* Wg = W + (size_t)(bx * 128) * K;

  // stage one BK=32 slab (A: 128x32, B: 128x32) into buffer `buf`
  auto stage = [&](int k0, int buf) {
#pragma unroll
    for (int it = 0; it < 2; ++it) {
      int base = it * 256 + wid * 64;   // chunk base (wave-uniform)
      int c = base + lane;              // chunk 0..511; rr = c>>2, col = c&3
      int rr = c >> 2;
      int bl = (c & 3) ^ ((rr >> 2) & 3);   // pre-swizzled source block
      gload_lds16(Ag + (size_t)rr * K + k0 + bl * 8, &As[buf * 4096 + base * 8]);
      gload_lds16(Wg + (size_t)rr * K + k0 + bl * 8, &Bs[buf * 4096 + base * 8]);
    }
  };

  stage(0, 0);
  stage(32, 1);
  asm volatile("s_waitcnt vmcnt(4)" ::: "memory");  // slab 0 landed
  __builtin_amdgcn_s_barrier();
  __builtin_amdgcn_sched_barrier(0);

  for (int kk = 0; kk < 32; ++kk) {
    int buf = kk % 3;
    bool pf = (kk + 2 < 32);
    if (pf) stage((kk + 2) * 32, (kk + 2) % 3);

    bf16x8 af[4], bf[4];
    int bl = g ^ ((r >> 2) & 3);
#pragma unroll
    for (int m = 0; m < 4; ++m) {
      int row = wm * 64 + m * 16 + r;
      af[m] = ld_frag(&As[buf * 4096 + row * 32 + bl * 8]);
    }
#pragma unroll
    for (int n = 0; n < 4; ++n) {
      int row = wn * 64 + n * 16 + r;
      bf[n] = ld_frag(&Bs[buf * 4096 + row * 32 + bl * 8]);
    }
    __builtin_amdgcn_s_setprio(1);
#pragma unroll
    for (int m = 0; m < 4; ++m)
#pragma unroll
      for (int n = 0; n < 4; ++n)
        acc[m][n] = __builtin_amdgcn_mfma_f32_16x16x32_bf16(af[m], bf[n], acc[m][n], 0, 0, 0);
    __builtin_amdgcn_s_setprio(0);

    // counted wait: slab kk+1 landed everywhere; slab kk+2 stays in flight
    if (pf) asm volatile("s_waitcnt vmcnt(4)" ::: "memory");
    else    asm volatile("s_waitcnt vmcnt(0)" ::: "memory");
    __builtin_amdgcn_s_barrier();
    __builtin_amdgcn_sched_barrier(0);
  }

#pragma unroll
  for (int m = 0; m < 4; ++m)
#pragma unroll
    for (int n = 0; n < 4; ++n) {
      int col = bx * 128 + wn * 64 + n * 16 + r;
      if (MODE == 2) {
        int hq = col >> 6, dq = col & 63;
        int row0 = by * 128 + wm * 64 + m * 16 + g * 4;
        int bq = row0 >> 11, tq = row0 & 2047;
        u16x4 pv;
#pragma unroll
        for (int j = 0; j < 4; ++j) pv[j] = f2bf(acc[m][n][j]);
        *(u16x4*)&Cb[(((size_t)(bq * NH + hq)) * HD + dq) * TB + tq] = pv;
      } else {
#pragma unroll
        for (int j = 0; j < 4; ++j) {
          int row = by * 128 + wm * 64 + m * 16 + g * 4 + j;
          if (MODE == 0)
            Cb[(size_t)row * N + col] = f2bf(acc[m][n][j]);
          else
            Cf[(size_t)row * N + col] = acc[m][n][j] + bias[col];
        }
      }
    }
}

__global__ __launch_bounds__(256) void k_gemm_qkv(
    const unsigned short* __restrict__ X,
    const unsigned short* __restrict__ Wq, const unsigned short* __restrict__ Wk,
    const unsigned short* __restrict__ Wv,
    unsigned short* __restrict__ Q, unsigned short* __restrict__ Kp,
    unsigned short* __restrict__ Vt) {
  __shared__ __align__(16) unsigned short As[12288];
  __shared__ __align__(16) unsigned short Bs[12288];
  // bijective XCD swizzle (768 = 8 x 96): XCD xcd owns by-panels 4*xcd..4*xcd+3
  int bidx = blockIdx.x;
  int xcd = bidx & 7, slot = bidx >> 3;
  int by = xcd * 4 + slot / 24;
  int bxx = slot % 24;
  int which = bxx >> 3, bx = bxx & 7;
  if (which == 2) {
    gemm_body<2>(X, Wv, Vt, nullptr, nullptr, by, bx, As, Bs);
  } else {
    const unsigned short* W = which ? Wk : Wq;
    unsigned short* C = which ? Kp : Q;
    gemm_body<0>(X, W, C, nullptr, nullptr, by, bx, As, Bs);
  }
}

__global__ __launch_bounds__(256) void k_gemm_out(
    const unsigned short* __restrict__ AO, const unsigned short* __restrict__ Wo,
    float* __restrict__ out, const float* __restrict__ bias) {
  __shared__ __align__(16) unsigned short As[12288];
  __shared__ __align__(16) unsigned short Bs[12288];
  // bijective XCD swizzle (256 = 8 x 32)
  int bidx = blockIdx.x;
  int xcd = bidx & 7, slot = bidx >> 3;
  int by = xcd * 4 + slot / 8;
  int bx = slot & 7;
  gemm_body<1>(AO, Wo, nullptr, out, bias, by, bx, As, Bs);
}

// ---------------- flash attention, 2 tiles per barrier period ----------------
// grid: 512 blocks (32 bh x 16 qt; bh = blockIdx&31 is XCD-affine) x 512 thr
// (8 waves). Wave w = (wl = w&3: 32 q-rows) x (kh = w>>2: key-half of each
// staged 64-key tile). 16 units x 2 tiles; double-buffered 2-tile units
// (64 KB LDS) with the PINNED sync idiom. FIXED-MAX softmax: P = exp(s/8-10).
// (LDS bank note: 128B rows => bank = 16B-column only; 64 lanes over 8 columns
// = 8 lanes/column is the b128 data-volume floor and the current swizzle
// balances columns perfectly — the constant 4.19M conflict count is floor.)
__global__ __launch_bounds__(512, 4) void k_attn(
    const unsigned short* __restrict__ Q, const unsigned short* __restrict__ Kp,
    const unsigned short* __restrict__ Vt, unsigned short* __restrict__ AO) {
  __shared__ __align__(16) unsigned short LDSb[8 * 4096];  // 64 KB
  unsigned short* KsB = LDSb;             // [buf][tt][64 keys][64 d], swizzled
  unsigned short* VsB = LDSb + 4 * 4096;  // [buf][tt][64 d][64 keys], swizzled

  int qt = blockIdx.x >> 5, bh = blockIdx.x & 31;
  int b = bh >> 4, h = bh & 15;
  int tid = threadIdx.x, lane = tid & 63, w = tid >> 6;
  int wl = w & 3, kh = w >> 2;
  int q = lane & 31, hh = lane >> 5;
  const float LOG2E = 1.44269504f;
  const int NU = 16;                // 16 units x 128 keys = 2048

  const unsigned short* Qp =
      Q + ((size_t)(b * TB + qt * 128 + wl * 32 + q)) * KDIM + h * HD;
  bf16x8 qf[4];
#pragma unroll
  for (int f = 0; f < 4; ++f) qf[f] = ld_frag(&Qp[16 * f + 8 * hh]);

  f32x16 o0, o1;
#pragma unroll
  for (int i = 0; i < 16; ++i) { o0[i] = 0.f; o1[i] = 0.f; }
  float l_run = 0.f;

  // staging addresses (each wave stages 1KB of K + 1KB of V per tile)
  int c = w * 64 + lane;
  int rr = c >> 3;
  int blk = (c & 7) ^ (rr & 7);            // pre-swizzled global source
  const unsigned short* Kg =
      Kp + (size_t)(b * TB) * KDIM + h * HD + (size_t)rr * KDIM + blk * 8;
  const unsigned short* Vg =
      Vt + (size_t)bh * HD * TB + (size_t)rr * TB + blk * 8;
  int ldst = w * 512;  // u16 offset of this wave's 1KB chunk

  auto stage = [&](int u, int buf) {
#pragma unroll
    for (int tt = 0; tt < 2; ++tt) {
      int kt = u * 2 + tt;
      int slot = buf * 2 + tt;
      gload_lds16(Kg + (size_t)kt * 64 * KDIM, &KsB[slot * 4096 + ldst]);
      gload_lds16(Vg + kt * 64, &VsB[slot * 4096 + ldst]);
    }
  };

  stage(0, 0);
  asm volatile("s_waitcnt vmcnt(0)" ::: "memory");
  __builtin_amdgcn_s_barrier();
  __builtin_amdgcn_sched_barrier(0);

  const float c1 = 0.125f * LOG2E;       // score scale folded into exp2
  const float c2 = 10.0f * LOG2E;        // fixed max shift
  f32x2 c1v; c1v[0] = c1; c1v[1] = c1;
  f32x2 c2v; c2v[0] = -c2; c2v[1] = -c2;

  for (int u = 0; u < NU; ++u) {
    int buf = u & 1;
    if (u + 1 < NU) stage(u + 1, buf ^ 1);

#pragma unroll
    for (int tt = 0; tt < 2; ++tt) {
      int slot = buf * 2 + tt;
      // S^T(32 keys x 32 q) = K_chunk @ Q^T
      const unsigned short* Kc = &KsB[slot * 4096];
      f32x16 st;
#pragma unroll
      for (int i = 0; i < 16; ++i) st[i] = 0.f;
      __builtin_amdgcn_s_setprio(1);
#pragma unroll
      for (int f = 0; f < 4; ++f) {
        int row = kh * 32 + q;
        int bl = (2 * f + hh) ^ (q & 7);
        bf16x8 kf = ld_frag(&Kc[row * 64 + bl * 8]);
        st = __builtin_amdgcn_mfma_f32_32x32x16_bf16(kf, qf[f], st, 0, 0, 0);
      }
      __builtin_amdgcn_s_setprio(0);

      // P = exp2(s*c1 - c2), packed bf16 fragments in-register (T12)
      f32x2 rsv; rsv[0] = 0.f; rsv[1] = 0.f;
      unsigned d[8];
#pragma unroll
      for (int i = 0; i < 8; ++i) {
        f32x2 p; p[0] = st[2 * i]; p[1] = st[2 * i + 1];
        p = pk_fma(p, c1v, c2v);
        f32x2 e; e[0] = fast_exp2(p[0]); e[1] = fast_exp2(p[1]);
        rsv = pk_add(rsv, e);
        d[i] = cvt_pk(e[0], e[1]);
      }
      u32x2 r1 = permswap(d[0], d[2]);
      u32x2 r2 = permswap(d[1], d[3]);
      u32x2 r3 = permswap(d[4], d[6]);
      u32x2 r4 = permswap(d[5], d[7]);
      u32x4 t0; t0[0] = r1.x; t0[1] = r2.x; t0[2] = r1.y; t0[3] = r2.y;
      u32x4 t1; t1[0] = r3.x; t1[1] = r4.x; t1[2] = r3.y; t1[3] = r4.y;
      bf16x8 pa0 = __builtin_bit_cast(bf16x8, t0);
      bf16x8 pa1 = __builtin_bit_cast(bf16x8, t1);
      float rs = rsv[0] + rsv[1];
      rs += __shfl_xor(rs, 32);
      l_run += rs;

      // O += P @ V (this wave's 32-key chunk)
      const unsigned short* Vc = &VsB[slot * 4096];
      __builtin_amdgcn_s_setprio(1);
      {
        int bl0 = (kh * 4 + hh) ^ (q & 7);
        int bl1 = (kh * 4 + 2 + hh) ^ (q & 7);
        bf16x8 v00 = ld_frag(&Vc[q * 64 + bl0 * 8]);
        bf16x8 v01 = ld_frag(&Vc[(32 + q) * 64 + bl0 * 8]);
        bf16x8 v10 = ld_frag(&Vc[q * 64 + bl1 * 8]);
        bf16x8 v11 = ld_frag(&Vc[(32 + q) * 64 + bl1 * 8]);
        o0 = __builtin_amdgcn_mfma_f32_32x32x16_bf16(pa0, v00, o0, 0, 0, 0);
        o1 = __builtin_amdgcn_mfma_f32_32x32x16_bf16(pa0, v01, o1, 0, 0, 0);
        o0 = __builtin_amdgcn_mfma_f32_32x32x16_bf16(pa1, v10, o0, 0, 0, 0);
        o1 = __builtin_amdgcn_mfma_f32_32x32x16_bf16(pa1, v11, o1, 0, 0, 0);
      }
      __builtin_amdgcn_s_setprio(0);
    }

    // pinned barrier: my stage(u+1) loads landed; everyone done reading buf
    asm volatile("s_waitcnt vmcnt(0)" ::: "memory");
    __builtin_amdgcn_s_barrier();
    __builtin_amdgcn_sched_barrier(0);
  }

  // -------- in-block kh merge via LDS (overlay on staging buffers) ----------
  float* Osw = (float*)LDSb;            // 32 KB
  float* MLb = Osw + 8192;              // 128 floats
  if (kh) {
#pragma unroll
    for (int p = 0; p < 16; ++p) {
      Osw[p * 256 + wl * 64 + lane]        = o0[p];
      Osw[(16 + p) * 256 + wl * 64 + lane] = o1[p];
    }
    if (!hh) MLb[wl * 32 + q] = l_run;
  }
  __syncthreads();
  if (!kh) {
    float il = 1.f / (l_run + MLb[wl * 32 + q]);
#pragma unroll
    for (int p = 0; p < 16; ++p) {
      int qr = (p & 3) + 8 * (p >> 2) + 4 * hh;
      float ip = __shfl(il, qr);
      float v0 = (o0[p] + Osw[p * 256 + wl * 64 + lane]) * ip;
      float v1 = (o1[p] + Osw[(16 + p) * 256 + wl * 64 + lane]) * ip;
      int row = qt * 128 + wl * 32 + qr;
      size_t base = ((size_t)(b * TB + row)) * KDIM + h * HD;
      AO[base + q]      = f2bf(v0);
      AO[base + 32 + q] = f2bf(v1);
    }
  }
}

// ---------------- launch ----------------
extern "C" void kernel_launch(void* const* d_in, const int* in_sizes, int n_in,
                              void* d_out, int out_size, void* d_ws, size_t ws_size,
                              hipStream_t stream) {
  const float* x  = (const float*)d_in[0];
  const float* Wq = (const float*)d_in[1];
  const float* Wk = (const float*)d_in[2];
  const float* Wv = (const float*)d_in[3];
  const float* Wo = (const float*)d_in[4];
  const float* bo = (const float*)d_in[5];

  char* ws = (char*)d_ws;
  const size_t MB = 1 << 20;
  unsigned short* xb  = (unsigned short*)(ws + 0 * MB);   // 8 MiB
  unsigned short* wqb = (unsigned short*)(ws + 8 * MB);   // 4 x 2 MiB contiguous
  unsigned short* wkb = (unsigned short*)(ws + 10 * MB);
  unsigned short* wvb = (unsigned short*)(ws + 12 * MB);
  unsigned short* wob = (unsigned short*)(ws + 14 * MB);
  unsigned short* Qb  = (unsigned short*)(ws + 16 * MB);  // 8 MiB
  unsigned short* Kb  = (unsigned short*)(ws + 24 * MB);
  unsigned short* Vtb = (unsigned short*)(ws + 32 * MB);
  unsigned short* AOb = (unsigned short*)(ws + 40 * MB);  // ends at 48 MiB

  k_cvt_all<<<4096, 256, 0, stream>>>(x, Wq, Wk, Wv, Wo, xb, wqb);
  k_gemm_qkv<<<32 * 24, 256, 0, stream>>>(xb, wqb, wkb, wvb, Qb, Kb, Vtb);
  k_attn<<<512, 512, 0, stream>>>(Qb, Kb, Vtb, AOb);
  k_gemm_out<<<256, 256, 0, stream>>>(AOb, wob, (float*)d_out, bo);
}

// Round 16
// 108.018 us; speedup vs baseline: 1.0665x; 1.0507x over previous
//
#include <hip/hip_runtime.h>
#include <stdint.h>
#include <stddef.h>

#define TB 2048
#define KDIM 1024
#define NH 16
#define HD 64

typedef __attribute__((ext_vector_type(8))) __bf16 bf16x8;
typedef __attribute__((ext_vector_type(2))) float f32x2;
typedef __attribute__((ext_vector_type(4))) float f32x4;
typedef __attribute__((ext_vector_type(16))) float f32x16;
typedef __attribute__((ext_vector_type(4))) unsigned short u16x4;
typedef __attribute__((ext_vector_type(8))) unsigned short u16x8;
typedef __attribute__((ext_vector_type(4))) unsigned u32x4;
typedef __attribute__((ext_vector_type(2))) unsigned u32x2;

static __device__ __forceinline__ unsigned short f2bf(float f) {
  unsigned u = __builtin_bit_cast(unsigned, f);
  return (unsigned short)((u + 0x7FFFu + ((u >> 16) & 1u)) >> 16);
}

static __device__ __forceinline__ bf16x8 ld_frag(const unsigned short* p) {
  u16x8 v = *(const u16x8*)p;
  return __builtin_bit_cast(bf16x8, v);
}

// global(16B per lane) -> LDS, linear lane order. LDS ptr must be wave-uniform.
static __device__ __forceinline__ void gload_lds16(const void* g, void* l) {
  auto gp = (const __attribute__((address_space(1))) unsigned int*)(uintptr_t)g;
  auto lp = (__attribute__((address_space(3))) unsigned int*)(unsigned int)(uintptr_t)l;
  __builtin_amdgcn_global_load_lds(gp, lp, 16, 0, 0);
}

static __device__ __forceinline__ float fast_exp2(float x) {
  float r;
  asm("v_exp_f32 %0, %1" : "=v"(r) : "v"(x));
  return r;
}

static __device__ __forceinline__ unsigned cvt_pk(float a, float b) {
  unsigned r;
  asm("v_cvt_pk_bf16_f32 %0, %1, %2" : "=v"(r) : "v"(a), "v"(b));
  return r;
}

static __device__ __forceinline__ u32x2 permswap(unsigned a, unsigned b) {
  return __builtin_amdgcn_permlane32_swap(a, b, false, false);
}

static __device__ __forceinline__ f32x2 pk_fma(f32x2 a, f32x2 b, f32x2 c) {
  f32x2 d;
  asm("v_pk_fma_f32 %0, %1, %2, %3" : "=v"(d) : "v"(a), "v"(b), "v"(c));
  return d;
}
static __device__ __forceinline__ f32x2 pk_add(f32x2 a, f32x2 b) {
  f32x2 d;
  asm("v_pk_add_f32 %0, %1, %2" : "=v"(d) : "v"(a), "v"(b));
  return d;
}

// ---------------- fused f32 -> bf16 convert (8 elems/thread) ----------------
__global__ __launch_bounds__(256) void k_cvt_all(
    const float* __restrict__ x, const float* __restrict__ Wq,
    const float* __restrict__ Wk, const float* __restrict__ Wv,
    const float* __restrict__ Wo, unsigned short* __restrict__ xb,
    unsigned short* __restrict__ wb) {
  int bb = blockIdx.x;
  const float* src;
  unsigned short* dst;
  int i;
  if (bb < 2048) {
    src = x; dst = xb; i = bb * 256 + threadIdx.x;
  } else {
    int wsel = (bb - 2048) >> 9;
    src = (wsel == 0) ? Wq : (wsel == 1) ? Wk : (wsel == 2) ? Wv : Wo;
    dst = wb + (size_t)wsel * (KDIM * KDIM);
    i = ((bb - 2048) & 511) * 256 + threadIdx.x;
  }
  const float4* p = (const float4*)src + (size_t)i * 2;
  float4 a = p[0], b = p[1];
  u16x8 o;
  o[0] = f2bf(a.x); o[1] = f2bf(a.y); o[2] = f2bf(a.z); o[3] = f2bf(a.w);
  o[4] = f2bf(b.x); o[5] = f2bf(b.y); o[6] = f2bf(b.z); o[7] = f2bf(b.w);
  *((u16x8*)dst + i) = o;
}

// ---------------- GEMM C = A @ W^T (A:[M,K] bf16, W:[N,K] bf16) ----------------
// 128xBN tile, BK=64, XOR-swizzled LDS, 4 waves (2 x 2), 16x16x32 MFMA.
// R13-proven 2-barrier body (pipelined variants R14/R15 were nulls: at >=2
// blocks/CU implicit wave overlap already covers the drain — m99/m131-m140).
// BN=128 for qkv (3 blocks/CU); BN=64 for the out-GEMM so its grid doubles to
// 512 = 2 blocks/CU (1 block/CU = 1 wave/SIMD had zero latency cover).
template <int MODE, int BN>  // MODE 0: bf16 out. 1: f32 out + bias. 2: Vt out.
static __device__ __forceinline__ void gemm_body(
    const unsigned short* __restrict__ A, const unsigned short* __restrict__ W,
    unsigned short* __restrict__ Cb, float* __restrict__ Cf,
    const float* __restrict__ bias, int by, int bx,
    unsigned short* As, unsigned short* Bs) {
  const int K = KDIM, N = KDIM;
  constexpr int NB = BN / 32;       // B frags per wave (4 or 2)
  constexpr int BIT = BN / 32;      // B stage iters (chunks = BN*8; 256/iter)
  int tid = threadIdx.x, lane = tid & 63, wid = tid >> 6;
  int r = lane & 15, g = lane >> 4;
  int wm = wid >> 1, wn = wid & 1;

  f32x4 acc[4][NB];
#pragma unroll
  for (int m = 0; m < 4; ++m)
#pragma unroll
    for (int n = 0; n < NB; ++n) acc[m][n] = (f32x4){0.f, 0.f, 0.f, 0.f};

  const unsigned short* Ag = A + (size_t)(by * 128) * K;
  const unsigned short* Wg = W + (size_t)(bx * BN) * K;

  for (int k0 = 0; k0 < K; k0 += 64) {
#pragma unroll
    for (int it = 0; it < 4; ++it) {
      int base = it * 256 + wid * 64;
      int c = base + lane;
      int rr = c >> 3;
      int blk = (c & 7) ^ (rr & 7);    // pre-swizzled source
      gload_lds16(Ag + (size_t)rr * K + k0 + blk * 8, &As[base * 8]);
    }
#pragma unroll
    for (int it = 0; it < BIT; ++it) {
      int base = it * 256 + wid * 64;
      int c = base + lane;
      int rr = c >> 3;
      int blk = (c & 7) ^ (rr & 7);
      gload_lds16(Wg + (size_t)rr * K + k0 + blk * 8, &Bs[base * 8]);
    }
    __syncthreads();
#pragma unroll
    for (int ks = 0; ks < 2; ++ks) {
      bf16x8 af[4], bf[NB];
#pragma unroll
      for (int m = 0; m < 4; ++m) {
        int row = wm * 64 + m * 16 + r;
        af[m] = ld_frag(&As[row * 64 + ((ks * 4 + g) ^ (r & 7)) * 8]);
      }
#pragma unroll
      for (int n = 0; n < NB; ++n) {
        int row = wn * (BN / 2) + n * 16 + r;
        bf[n] = ld_frag(&Bs[row * 64 + ((ks * 4 + g) ^ (r & 7)) * 8]);
      }
      __builtin_amdgcn_s_setprio(1);
#pragma unroll
      for (int m = 0; m < 4; ++m)
#pragma unroll
        for (int n = 0; n < NB; ++n)
          acc[m][n] = __builtin_amdgcn_mfma_f32_16x16x32_bf16(af[m], bf[n], acc[m][n], 0, 0, 0);
      __builtin_amdgcn_s_setprio(0);
    }
    __syncthreads();
  }

#pragma unroll
  for (int m = 0; m < 4; ++m)
#pragma unroll
    for (int n = 0; n < NB; ++n) {
      int col = bx * BN + wn * (BN / 2) + n * 16 + r;
      if (MODE == 2) {
        int hq = col >> 6, dq = col & 63;
        int row0 = by * 128 + wm * 64 + m * 16 + g * 4;
        int bq = row0 >> 11, tq = row0 & 2047;
        u16x4 pv;
#pragma unroll
        for (int j = 0; j < 4; ++j) pv[j] = f2bf(acc[m][n][j]);
        *(u16x4*)&Cb[(((size_t)(bq * NH + hq)) * HD + dq) * TB + tq] = pv;
      } else {
#pragma unroll
        for (int j = 0; j < 4; ++j) {
          int row = by * 128 + wm * 64 + m * 16 + g * 4 + j;
          if (MODE == 0)
            Cb[(size_t)row * N + col] = f2bf(acc[m][n][j]);
          else
            Cf[(size_t)row * N + col] = acc[m][n][j] + bias[col];
        }
      }
    }
}

__global__ __launch_bounds__(256) void k_gemm_qkv(
    const unsigned short* __restrict__ X,
    const unsigned short* __restrict__ Wq, const unsigned short* __restrict__ Wk,
    const unsigned short* __restrict__ Wv,
    unsigned short* __restrict__ Q, unsigned short* __restrict__ Kp,
    unsigned short* __restrict__ Vt) {
  __shared__ __align__(16) unsigned short As[8192];
  __shared__ __align__(16) unsigned short Bs[8192];
  // bijective XCD swizzle (768 = 8 x 96): XCD xcd owns by-panels 4*xcd..4*xcd+3
  int bidx = blockIdx.x;
  int xcd = bidx & 7, slot = bidx >> 3;
  int by = xcd * 4 + slot / 24;
  int bxx = slot % 24;
  int which = bxx >> 3, bx = bxx & 7;
  if (which == 2) {
    gemm_body<2, 128>(X, Wv, Vt, nullptr, nullptr, by, bx, As, Bs);
  } else {
    const unsigned short* W = which ? Wk : Wq;
    unsigned short* C = which ? Kp : Q;
    gemm_body<0, 128>(X, W, C, nullptr, nullptr, by, bx, As, Bs);
  }
}

__global__ __launch_bounds__(256) void k_gemm_out(
    const unsigned short* __restrict__ AO, const unsigned short* __restrict__ Wo,
    float* __restrict__ out, const float* __restrict__ bias) {
  __shared__ __align__(16) unsigned short As[8192];
  __shared__ __align__(16) unsigned short Bs[4096];
  // grid 512 = 32 by x 16 bx; bijective XCD swizzle (8 x 64)
  int bidx = blockIdx.x;
  int xcd = bidx & 7, slot = bidx >> 3;
  int by = xcd * 4 + slot / 16;
  int bx = slot & 15;
  gemm_body<1, 64>(AO, Wo, nullptr, out, bias, by, bx, As, Bs);
}

// ---------------- flash attention, 2 tiles per barrier period ----------------
// grid: 512 blocks (32 bh x 16 qt; bh = blockIdx&31 is XCD-affine) x 512 thr
// (8 waves). Wave w = (wl = w&3: 32 q-rows) x (kh = w>>2: key-half of each
// staged 64-key tile). 16 units x 2 tiles; double-buffered 2-tile units
// (64 KB LDS) with the PINNED sync idiom. FIXED-MAX softmax: P = exp(s/8-10).
__global__ __launch_bounds__(512, 4) void k_attn(
    const unsigned short* __restrict__ Q, const unsigned short* __restrict__ Kp,
    const unsigned short* __restrict__ Vt, unsigned short* __restrict__ AO) {
  __shared__ __align__(16) unsigned short LDSb[8 * 4096];  // 64 KB
  unsigned short* KsB = LDSb;             // [buf][tt][64 keys][64 d], swizzled
  unsigned short* VsB = LDSb + 4 * 4096;  // [buf][tt][64 d][64 keys], swizzled

  int qt = blockIdx.x >> 5, bh = blockIdx.x & 31;
  int b = bh >> 4, h = bh & 15;
  int tid = threadIdx.x, lane = tid & 63, w = tid >> 6;
  int wl = w & 3, kh = w >> 2;
  int q = lane & 31, hh = lane >> 5;
  const float LOG2E = 1.44269504f;
  const int NU = 16;                // 16 units x 128 keys = 2048

  const unsigned short* Qp =
      Q + ((size_t)(b * TB + qt * 128 + wl * 32 + q)) * KDIM + h * HD;
  bf16x8 qf[4];
#pragma unroll
  for (int f = 0; f < 4; ++f) qf[f] = ld_frag(&Qp[16 * f + 8 * hh]);

  f32x16 o0, o1;
#pragma unroll
  for (int i = 0; i < 16; ++i) { o0[i] = 0.f; o1[i] = 0.f; }
  float l_run = 0.f;

  // staging addresses (each wave stages 1KB of K + 1KB of V per tile)
  int c = w * 64 + lane;
  int rr = c >> 3;
  int blk = (c & 7) ^ (rr & 7);            // pre-swizzled global source
  const unsigned short* Kg =
      Kp + (size_t)(b * TB) * KDIM + h * HD + (size_t)rr * KDIM + blk * 8;
  const unsigned short* Vg =
      Vt + (size_t)bh * HD * TB + (size_t)rr * TB + blk * 8;
  int ldst = w * 512;  // u16 offset of this wave's 1KB chunk

  auto stage = [&](int u, int buf) {
#pragma unroll
    for (int tt = 0; tt < 2; ++tt) {
      int kt = u * 2 + tt;
      int slot = buf * 2 + tt;
      gload_lds16(Kg + (size_t)kt * 64 * KDIM, &KsB[slot * 4096 + ldst]);
      gload_lds16(Vg + kt * 64, &VsB[slot * 4096 + ldst]);
    }
  };

  stage(0, 0);
  asm volatile("s_waitcnt vmcnt(0)" ::: "memory");
  __builtin_amdgcn_s_barrier();
  __builtin_amdgcn_sched_barrier(0);

  const float c1 = 0.125f * LOG2E;       // score scale folded into exp2
  const float c2 = 10.0f * LOG2E;        // fixed max shift
  f32x2 c1v; c1v[0] = c1; c1v[1] = c1;
  f32x2 c2v; c2v[0] = -c2; c2v[1] = -c2;

  for (int u = 0; u < NU; ++u) {
    int buf = u & 1;
    if (u + 1 < NU) stage(u + 1, buf ^ 1);

#pragma unroll
    for (int tt = 0; tt < 2; ++tt) {
      int slot = buf * 2 + tt;
      // S^T(32 keys x 32 q) = K_chunk @ Q^T
      const unsigned short* Kc = &KsB[slot * 4096];
      f32x16 st;
#pragma unroll
      for (int i = 0; i < 16; ++i) st[i] = 0.f;
      __builtin_amdgcn_s_setprio(1);
#pragma unroll
      for (int f = 0; f < 4; ++f) {
        int row = kh * 32 + q;
        int bl = (2 * f + hh) ^ (q & 7);
        bf16x8 kf = ld_frag(&Kc[row * 64 + bl * 8]);
        st = __builtin_amdgcn_mfma_f32_32x32x16_bf16(kf, qf[f], st, 0, 0, 0);
      }
      __builtin_amdgcn_s_setprio(0);

      // P = exp2(s*c1 - c2), packed bf16 fragments in-register (T12)
      f32x2 rsv; rsv[0] = 0.f; rsv[1] = 0.f;
      unsigned d[8];
#pragma unroll
      for (int i = 0; i < 8; ++i) {
        f32x2 p; p[0] = st[2 * i]; p[1] = st[2 * i + 1];
        p = pk_fma(p, c1v, c2v);
        f32x2 e; e[0] = fast_exp2(p[0]); e[1] = fast_exp2(p[1]);
        rsv = pk_add(rsv, e);
        d[i] = cvt_pk(e[0], e[1]);
      }
      u32x2 r1 = permswap(d[0], d[2]);
      u32x2 r2 = permswap(d[1], d[3]);
      u32x2 r3 = permswap(d[4], d[6]);
      u32x2 r4 = permswap(d[5], d[7]);
      u32x4 t0; t0[0] = r1.x; t0[1] = r2.x; t0[2] = r1.y; t0[3] = r2.y;
      u32x4 t1; t1[0] = r3.x; t1[1] = r4.x; t1[2] = r3.y; t1[3] = r4.y;
      bf16x8 pa0 = __builtin_bit_cast(bf16x8, t0);
      bf16x8 pa1 = __builtin_bit_cast(bf16x8, t1);
      float rs = rsv[0] + rsv[1];
      rs += __shfl_xor(rs, 32);
      l_run += rs;

      // O += P @ V (this wave's 32-key chunk)
      const unsigned short* Vc = &VsB[slot * 4096];
      __builtin_amdgcn_s_setprio(1);
      {
        int bl0 = (kh * 4 + hh) ^ (q & 7);
        int bl1 = (kh * 4 + 2 + hh) ^ (q & 7);
        bf16x8 v00 = ld_frag(&Vc[q * 64 + bl0 * 8]);
        bf16x8 v01 = ld_frag(&Vc[(32 + q) * 64 + bl0 * 8]);
        bf16x8 v10 = ld_frag(&Vc[q * 64 + bl1 * 8]);
        bf16x8 v11 = ld_frag(&Vc[(32 + q) * 64 + bl1 * 8]);
        o0 = __builtin_amdgcn_mfma_f32_32x32x16_bf16(pa0, v00, o0, 0, 0, 0);
        o1 = __builtin_amdgcn_mfma_f32_32x32x16_bf16(pa0, v01, o1, 0, 0, 0);
        o0 = __builtin_amdgcn_mfma_f32_32x32x16_bf16(pa1, v10, o0, 0, 0, 0);
        o1 = __builtin_amdgcn_mfma_f32_32x32x16_bf16(pa1, v11, o1, 0, 0, 0);
      }
      __builtin_amdgcn_s_setprio(0);
    }

    // pinned barrier: my stage(u+1) loads landed; everyone done reading buf
    asm volatile("s_waitcnt vmcnt(0)" ::: "memory");
    __builtin_amdgcn_s_barrier();
    __builtin_amdgcn_sched_barrier(0);
  }

  // -------- in-block kh merge via LDS (overlay on staging buffers) ----------
  float* Osw = (float*)LDSb;            // 32 KB
  float* MLb = Osw + 8192;              // 128 floats
  if (kh) {
#pragma unroll
    for (int p = 0; p < 16; ++p) {
      Osw[p * 256 + wl * 64 + lane]        = o0[p];
      Osw[(16 + p) * 256 + wl * 64 + lane] = o1[p];
    }
    if (!hh) MLb[wl * 32 + q] = l_run;
  }
  __syncthreads();
  if (!kh) {
    float il = 1.f / (l_run + MLb[wl * 32 + q]);
#pragma unroll
    for (int p = 0; p < 16; ++p) {
      int qr = (p & 3) + 8 * (p >> 2) + 4 * hh;
      float ip = __shfl(il, qr);
      float v0 = (o0[p] + Osw[p * 256 + wl * 64 + lane]) * ip;
      float v1 = (o1[p] + Osw[(16 + p) * 256 + wl * 64 + lane]) * ip;
      int row = qt * 128 + wl * 32 + qr;
      size_t base = ((size_t)(b * TB + row)) * KDIM + h * HD;
      AO[base + q]      = f2bf(v0);
      AO[base + 32 + q] = f2bf(v1);
    }
  }
}

// ---------------- launch ----------------
extern "C" void kernel_launch(void* const* d_in, const int* in_sizes, int n_in,
                              void* d_out, int out_size, void* d_ws, size_t ws_size,
                              hipStream_t stream) {
  const float* x  = (const float*)d_in[0];
  const float* Wq = (const float*)d_in[1];
  const float* Wk = (const float*)d_in[2];
  const float* Wv = (const float*)d_in[3];
  const float* Wo = (const float*)d_in[4];
  const float* bo = (const float*)d_in[5];

  char* ws = (char*)d_ws;
  const size_t MB = 1 << 20;
  unsigned short* xb  = (unsigned short*)(ws + 0 * MB);   // 8 MiB
  unsigned short* wqb = (unsigned short*)(ws + 8 * MB);   // 4 x 2 MiB contiguous
  unsigned short* wkb = (unsigned short*)(ws + 10 * MB);
  unsigned short* wvb = (unsigned short*)(ws + 12 * MB);
  unsigned short* wob = (unsigned short*)(ws + 14 * MB);
  unsigned short* Qb  = (unsigned short*)(ws + 16 * MB);  // 8 MiB
  unsigned short* Kb  = (unsigned short*)(ws + 24 * MB);
  unsigned short* Vtb = (unsigned short*)(ws + 32 * MB);
  unsigned short* AOb = (unsigned short*)(ws + 40 * MB);  // ends at 48 MiB

  k_cvt_all<<<4096, 256, 0, stream>>>(x, Wq, Wk, Wv, Wo, xb, wqb);
  k_gemm_qkv<<<32 * 24, 256, 0, stream>>>(xb, wqb, wkb, wvb, Qb, Kb, Vtb);
  k_attn<<<512, 512, 0, stream>>>(Qb, Kb, Vtb, AOb);
  k_gemm_out<<<512, 256, 0, stream>>>(AOb, wob, (float*)d_out, bo);
}